// Round 1
// baseline (192.705 us; speedup 1.0000x reference)
//
#include <hip/hip_runtime.h>
#include <math.h>

#define TTOK 8192
#define DIM  2048
#define NEXP 16
#define NH   1024

// ---- workspace layout (float offsets) ----
#define OFF_PART1   0u                        // [16][8192][16]
#define OFF_LOGITS  2097152u                  // [8192][16]
#define OFF_COMBINE 2228224u                  // [8192][16]
#define OFF_NUM     2359296u                  // [8192][16]
#define OFF_PART6   2490368u                  // [64][16][2048]
#define OFF_RAWH    4587520u                  // [16][16][1024]
#define OFF_PART10  4849664u                  // [16][16][2048]
#define OFF_SLOTOUT 5373952u                  // [16][2048]
#define OFF_CMAX    5406720u                  // [32][16]
#define OFF_CSUM    5407232u                  // [32][16]
#define OFF_MUSUM   5407744u                  // [32][16]
#define OFF_ENT     5408256u                  // [32]
#define OFF_M       5408288u                  // [16]
#define OFF_INVS    5408304u                  // [16]

// ---- d_out layout (float offsets) ----
#define O_OUT   0u
#define O_LOSS  16777216u
#define O_GATE  16777217u
#define O_TOPI  16908289u
#define O_TOPW  16924673u
#define O_MU    16941057u
#define O_ENTR  16941073u
#define O_DISP  16941074u

__device__ __forceinline__ float wave_sum(float v){
  #pragma unroll
  for (int o=1;o<64;o<<=1) v += __shfl_xor(v,o,64);
  return v;
}
__device__ __forceinline__ float wave_max(float v){
  #pragma unroll
  for (int o=1;o<64;o<<=1) v = fmaxf(v,__shfl_xor(v,o,64));
  return v;
}

// K1: logits partials. grid 512 = 32 token-blocks x 16 k-chunks(128)
__global__ __launch_bounds__(256) void k1_logits(const float* __restrict__ x,
                                                 const float* __restrict__ Wd,
                                                 float* __restrict__ part1){
  const int tb = blockIdx.x >> 4;
  const int kc = blockIdx.x & 15;
  const int t  = tb*256 + threadIdx.x;
  const float4* __restrict__ xr = (const float4*)(x + (size_t)t*DIM + kc*128);
  float acc[16];
  #pragma unroll
  for (int e=0;e<16;e++) acc[e]=0.f;
  #pragma unroll 4
  for (int k4=0;k4<32;k4++){
    float4 xv = xr[k4];
    #pragma unroll
    for (int e=0;e<16;e++){
      float4 w = *(const float4*)(Wd + e*DIM + kc*128 + k4*4);
      acc[e] += xv.x*w.x + xv.y*w.y + xv.z*w.z + xv.w*w.w;
    }
  }
  float4* po = (float4*)(part1 + ((size_t)kc*TTOK + t)*16);
  po[0] = make_float4(acc[0],acc[1],acc[2],acc[3]);
  po[1] = make_float4(acc[4],acc[5],acc[6],acc[7]);
  po[2] = make_float4(acc[8],acc[9],acc[10],acc[11]);
  po[3] = make_float4(acc[12],acc[13],acc[14],acc[15]);
}

// K2: reduce partials -> logits; row softmax (combine); gate/topk/entropy outputs;
// block partials for colmax / mean_usage / entropy. grid 32 x 256
__global__ __launch_bounds__(256) void k2_row(const float* __restrict__ part1,
    float* __restrict__ logits, float* __restrict__ combine,
    float* __restrict__ gate_out, float* __restrict__ topi_out, float* __restrict__ topw_out,
    float* __restrict__ colmax_part, float* __restrict__ musum_part, float* __restrict__ ent_part){
  const int tid = threadIdx.x;
  const int t = blockIdx.x*256 + tid;
  float l[16];
  #pragma unroll
  for (int e=0;e<16;e++) l[e]=0.f;
  for (int kc=0;kc<16;kc++){
    const float4* pr = (const float4*)(part1 + ((size_t)kc*TTOK + t)*16);
    #pragma unroll
    for (int q=0;q<4;q++){
      float4 v = pr[q];
      l[q*4+0]+=v.x; l[q*4+1]+=v.y; l[q*4+2]+=v.z; l[q*4+3]+=v.w;
    }
  }
  float4* lo = (float4*)(logits + (size_t)t*16);
  lo[0]=make_float4(l[0],l[1],l[2],l[3]);   lo[1]=make_float4(l[4],l[5],l[6],l[7]);
  lo[2]=make_float4(l[8],l[9],l[10],l[11]); lo[3]=make_float4(l[12],l[13],l[14],l[15]);
  float m = l[0];
  #pragma unroll
  for (int e=1;e<16;e++) m = fmaxf(m,l[e]);
  float c[16]; float s=0.f;
  #pragma unroll
  for (int e=0;e<16;e++){ c[e]=expf(l[e]-m); s+=c[e]; }
  float inv = 1.f/s;
  #pragma unroll
  for (int e=0;e<16;e++) c[e]*=inv;
  float4* co = (float4*)(combine + (size_t)t*16);
  co[0]=make_float4(c[0],c[1],c[2],c[3]);   co[1]=make_float4(c[4],c[5],c[6],c[7]);
  co[2]=make_float4(c[8],c[9],c[10],c[11]); co[3]=make_float4(c[12],c[13],c[14],c[15]);
  // gate output region is only 4B-aligned -> scalar stores
  float* go = gate_out + (size_t)t*16;
  #pragma unroll
  for (int e=0;e<16;e++) go[e]=c[e];
  // top-2 (stable: strict > keeps lowest index on ties, matching lax.top_k)
  float v0=-1.f, v1=-1.f; int i0=0, i1=0;
  #pragma unroll
  for (int e=0;e<16;e++){
    float ce=c[e];
    if (ce>v0){ v1=v0; i1=i0; v0=ce; i0=e; }
    else if (ce>v1){ v1=ce; i1=e; }
  }
  float dn = fmaxf(v0+v1, 1e-8f);
  topi_out[(size_t)t*2+0]=(float)i0; topi_out[(size_t)t*2+1]=(float)i1;
  topw_out[(size_t)t*2+0]=v0/dn;     topw_out[(size_t)t*2+1]=v1/dn;
  float ent=0.f;
  #pragma unroll
  for (int e=0;e<16;e++) ent -= c[e]*logf(c[e]+1e-8f);

  __shared__ float red[4][16];
  __shared__ float rede[4];
  const int w = tid>>6, lane = tid&63;
  #pragma unroll
  for (int e=0;e<16;e++){ float v=wave_max(l[e]); if(lane==0) red[w][e]=v; }
  __syncthreads();
  if (tid<16){
    float v=fmaxf(fmaxf(red[0][tid],red[1][tid]),fmaxf(red[2][tid],red[3][tid]));
    colmax_part[blockIdx.x*16+tid]=v;
  }
  __syncthreads();
  #pragma unroll
  for (int e=0;e<16;e++){ float v=wave_sum(c[e]); if(lane==0) red[w][e]=v; }
  { float v=wave_sum(ent); if(lane==0) rede[w]=v; }
  __syncthreads();
  if (tid<16) musum_part[blockIdx.x*16+tid]=red[0][tid]+red[1][tid]+red[2][tid]+red[3][tid];
  if (tid==0) ent_part[blockIdx.x]=rede[0]+rede[1]+rede[2]+rede[3];
}

// K3: finalize colmax -> m; mean_usage; entropy; p from Wd; router_loss. 1 block x 256
__global__ __launch_bounds__(256) void k3_finalize(const float* __restrict__ Wd,
    const float* __restrict__ colmax_part, const float* __restrict__ musum_part,
    const float* __restrict__ ent_part,
    float* __restrict__ m_ws, float* __restrict__ loss_out,
    float* __restrict__ mu_out, float* __restrict__ ent_out){
  const int tid = threadIdx.x;
  __shared__ float sq[16][16];
  __shared__ float smu[16];
  __shared__ float sqe[16];
  {
    int s = tid>>4, e = tid&15;
    const float* base = Wd + (size_t)s*DIM + e*128;
    float q=0.f;
    for (int i=0;i<128;i+=4){ float4 v=*(const float4*)(base+i); q+=v.x+v.y+v.z+v.w; }
    sq[s][e]=q;
  }
  if (tid<16){
    float mm=-INFINITY, mu=0.f;
    for (int b=0;b<32;b++){ mm=fmaxf(mm,colmax_part[b*16+tid]); mu+=musum_part[b*16+tid]; }
    m_ws[tid]=mm;
    mu/=8192.f;
    mu_out[tid]=mu; smu[tid]=mu;
  }
  if (tid==32){ float es=0.f; for(int b=0;b<32;b++) es+=ent_part[b]; ent_out[0]=es/8192.f; }
  __syncthreads();
  __shared__ float sqv[16];
  if (tid<16){ float q=0.f; for(int s=0;s<16;s++) q+=sq[s][tid]; sqv[tid]=q/2048.f; }
  __syncthreads();
  if (tid<16){
    float qm=-INFINITY;
    for (int e=0;e<16;e++) qm=fmaxf(qm,sqv[e]);
    sqe[tid]=expf(sqv[tid]-qm);
  }
  __syncthreads();
  if (tid==0){
    float qs=0.f; for(int e=0;e<16;e++) qs+=sqe[e];
    float loss=0.f; for(int e=0;e<16;e++) loss+=smu[e]*(sqe[e]/qs);
    loss_out[0]=16.f*loss;
  }
}

// K4: num = exp(logits - colmax); colsum partials. grid 32 x 256
__global__ __launch_bounds__(256) void k4_num(const float* __restrict__ logits,
    const float* __restrict__ m_ws, float* __restrict__ num, float* __restrict__ colsum_part){
  const int tid=threadIdx.x;
  const int t=blockIdx.x*256+tid;
  float mm[16];
  {
    const float4* mp=(const float4*)m_ws;
    #pragma unroll
    for (int q=0;q<4;q++){ float4 v=mp[q]; mm[q*4]=v.x; mm[q*4+1]=v.y; mm[q*4+2]=v.z; mm[q*4+3]=v.w; }
  }
  const float4* lr=(const float4*)(logits+(size_t)t*16);
  float n[16];
  #pragma unroll
  for (int q=0;q<4;q++){
    float4 v=lr[q];
    n[q*4+0]=expf(v.x-mm[q*4+0]); n[q*4+1]=expf(v.y-mm[q*4+1]);
    n[q*4+2]=expf(v.z-mm[q*4+2]); n[q*4+3]=expf(v.w-mm[q*4+3]);
  }
  float4* no=(float4*)(num+(size_t)t*16);
  no[0]=make_float4(n[0],n[1],n[2],n[3]);   no[1]=make_float4(n[4],n[5],n[6],n[7]);
  no[2]=make_float4(n[8],n[9],n[10],n[11]); no[3]=make_float4(n[12],n[13],n[14],n[15]);
  __shared__ float red[4][16];
  const int w=tid>>6, lane=tid&63;
  #pragma unroll
  for (int e=0;e<16;e++){ float v=wave_sum(n[e]); if(lane==0) red[w][e]=v; }
  __syncthreads();
  if (tid<16) colsum_part[blockIdx.x*16+tid]=red[0][tid]+red[1][tid]+red[2][tid]+red[3][tid];
}

// K5: inv_s. 1 block x 64
__global__ void k5_invs(const float* __restrict__ colsum_part, float* __restrict__ inv_s){
  int tid=threadIdx.x;
  if (tid<16){ float s=0.f; for(int b=0;b<32;b++) s+=colsum_part[b*16+tid]; inv_s[tid]=1.f/s; }
}

// K5b: dispatch output (4B-aligned region -> scalar). grid 512 x 256
__global__ __launch_bounds__(256) void k5b_disp(const float* __restrict__ num,
    const float* __restrict__ inv_s, float* __restrict__ disp_out){
  int i = blockIdx.x*256 + threadIdx.x;          // 131072 total
  disp_out[i] = num[i]*inv_s[i&15];
}

// K6: slot_in raw partials: part6[tc][e][d] = sum_t num[t][e]*x[t][d]. grid 256 = 64tc x 4dc
__global__ __launch_bounds__(256) void k6_slotin(const float* __restrict__ x,
    const float* __restrict__ num, float* __restrict__ part6){
  const int tc = blockIdx.x >> 2;
  const int dc = blockIdx.x & 3;
  const int d  = dc*512 + threadIdx.x*2;
  const int t0 = tc*128;
  float2 acc[16];
  #pragma unroll
  for (int e=0;e<16;e++){ acc[e].x=0.f; acc[e].y=0.f; }
  #pragma unroll 4
  for (int t=0;t<128;t++){
    float2 xv = *(const float2*)(x + (size_t)(t0+t)*DIM + d);
    const float* nr = num + (size_t)(t0+t)*16;
    #pragma unroll
    for (int e=0;e<16;e++){
      float nv = nr[e];
      acc[e].x = fmaf(nv,xv.x,acc[e].x);
      acc[e].y = fmaf(nv,xv.y,acc[e].y);
    }
  }
  #pragma unroll
  for (int e=0;e<16;e++)
    *(float2*)(part6 + ((size_t)tc*16+e)*DIM + d) = acc[e];
}

// K8: rawh partials = W1^T @ slot_raw over d-chunk. grid 256 = 16e x 16dc
__global__ __launch_bounds__(256) void k8_h(const float* __restrict__ part6,
    const float* __restrict__ W1, float* __restrict__ rawh){
  const int e   = blockIdx.x >> 4;
  const int dcc = blockIdx.x & 15;
  const int dbase = dcc*128;
  const int tid = threadIdx.x;
  __shared__ float sl[128];
  if (tid<128){
    float s=0.f;
    for (int tc=0;tc<64;tc++) s += part6[((size_t)tc*16+e)*DIM + dbase + tid];
    sl[tid]=s;
  }
  __syncthreads();
  const int hq = tid*4;
  float4 acc = make_float4(0.f,0.f,0.f,0.f);
  #pragma unroll 8
  for (int d=0; d<128; d++){
    float4 w = *(const float4*)(W1 + ((size_t)e*DIM + dbase + d)*NH + hq);
    float s = sl[d];
    acc.x=fmaf(s,w.x,acc.x); acc.y=fmaf(s,w.y,acc.y);
    acc.z=fmaf(s,w.z,acc.z); acc.w=fmaf(s,w.w,acc.w);
  }
  *(float4*)(rawh + ((size_t)dcc*16+e)*NH + hq) = acc;
}

// K10: h = gelu(inv_s*rawh + b1); slot_out partials over h-chunk. grid 256 = 16e x 16hc
__global__ __launch_bounds__(256) void k10_so(const float* __restrict__ rawh,
    const float* __restrict__ W2, const float* __restrict__ b1,
    const float* __restrict__ inv_s, float* __restrict__ part10){
  const int e  = blockIdx.x >> 4;
  const int hc = blockIdx.x & 15;
  const int hbase = hc*64;
  const int tid = threadIdx.x;
  __shared__ float hh[64];
  if (tid<64){
    float s=0.f;
    for (int dcc=0;dcc<16;dcc++) s += rawh[((size_t)dcc*16+e)*NH + hbase + tid];
    float pre = inv_s[e]*s + b1[(size_t)e*NH + hbase + tid];
    hh[tid] = 0.5f*pre*(1.f+erff(pre*0.70710678118654752f));
  }
  __syncthreads();
  const int d0 = tid*4, d1 = (tid+256)*4;
  float4 a0=make_float4(0,0,0,0), a1=make_float4(0,0,0,0);
  #pragma unroll 4
  for (int j=0;j<64;j++){
    const float* wrow = W2 + ((size_t)e*NH + hbase + j)*DIM;
    float4 w0 = *(const float4*)(wrow + d0);
    float4 w1 = *(const float4*)(wrow + d1);
    float s = hh[j];
    a0.x=fmaf(s,w0.x,a0.x); a0.y=fmaf(s,w0.y,a0.y); a0.z=fmaf(s,w0.z,a0.z); a0.w=fmaf(s,w0.w,a0.w);
    a1.x=fmaf(s,w1.x,a1.x); a1.y=fmaf(s,w1.y,a1.y); a1.z=fmaf(s,w1.z,a1.z); a1.w=fmaf(s,w1.w,a1.w);
  }
  *(float4*)(part10 + ((size_t)hc*16+e)*DIM + d0) = a0;
  *(float4*)(part10 + ((size_t)hc*16+e)*DIM + d1) = a1;
}

// K11: slot_out = sum_hc part10 + b2. grid 128 x 256
__global__ __launch_bounds__(256) void k11_sofin(const float* __restrict__ part10,
    const float* __restrict__ b2, float* __restrict__ slot_out){
  int i = blockIdx.x*256 + threadIdx.x;     // 32768
  float s=0.f;
  #pragma unroll
  for (int hc=0;hc<16;hc++) s += part10[(size_t)hc*32768 + i];
  slot_out[i] = s + b2[i];
}

// K12: out = combine @ slot_out. grid 512 = 256tb x 2dc
__global__ __launch_bounds__(256) void k12_out(const float* __restrict__ slot_out,
    const float* __restrict__ combine, float* __restrict__ out){
  const int tb = blockIdx.x >> 1;
  const int dc = blockIdx.x & 1;
  const int t0 = tb*32;
  const int d  = dc*1024 + threadIdx.x*4;
  float4 sv[16];
  #pragma unroll
  for (int e=0;e<16;e++) sv[e] = *(const float4*)(slot_out + (size_t)e*DIM + d);
  for (int t=0;t<32;t++){
    const float* cr = combine + (size_t)(t0+t)*16;
    float4 a = make_float4(0,0,0,0);
    #pragma unroll
    for (int e=0;e<16;e++){
      float c = cr[e];
      a.x=fmaf(c,sv[e].x,a.x); a.y=fmaf(c,sv[e].y,a.y);
      a.z=fmaf(c,sv[e].z,a.z); a.w=fmaf(c,sv[e].w,a.w);
    }
    *(float4*)(out + (size_t)(t0+t)*DIM + d) = a;
  }
}

extern "C" void kernel_launch(void* const* d_in, const int* in_sizes, int n_in,
                              void* d_out, int out_size, void* d_ws, size_t ws_size,
                              hipStream_t stream) {
  const float* x  = (const float*)d_in[0];
  const float* Wd = (const float*)d_in[1];
  const float* W1 = (const float*)d_in[2];
  const float* b1 = (const float*)d_in[3];
  const float* W2 = (const float*)d_in[4];
  const float* b2 = (const float*)d_in[5];
  float* out = (float*)d_out;
  float* ws  = (float*)d_ws;

  float* part1   = ws + OFF_PART1;
  float* logits  = ws + OFF_LOGITS;
  float* combine = ws + OFF_COMBINE;
  float* num     = ws + OFF_NUM;
  float* part6   = ws + OFF_PART6;
  float* rawh    = ws + OFF_RAWH;
  float* part10  = ws + OFF_PART10;
  float* slot_out= ws + OFF_SLOTOUT;
  float* cmaxp   = ws + OFF_CMAX;
  float* csump   = ws + OFF_CSUM;
  float* musump  = ws + OFF_MUSUM;
  float* entp    = ws + OFF_ENT;
  float* m_ws    = ws + OFF_M;
  float* inv_s   = ws + OFF_INVS;

  float* o_out  = out + O_OUT;
  float* o_loss = out + O_LOSS;
  float* o_gate = out + O_GATE;
  float* o_topi = out + O_TOPI;
  float* o_topw = out + O_TOPW;
  float* o_mu   = out + O_MU;
  float* o_ent  = out + O_ENTR;
  float* o_disp = out + O_DISP;

  k1_logits<<<512, 256, 0, stream>>>(x, Wd, part1);
  k2_row<<<32, 256, 0, stream>>>(part1, logits, combine, o_gate, o_topi, o_topw,
                                 cmaxp, musump, entp);
  k3_finalize<<<1, 256, 0, stream>>>(Wd, cmaxp, musump, entp, m_ws, o_loss, o_mu, o_ent);
  k4_num<<<32, 256, 0, stream>>>(logits, m_ws, num, csump);
  k5_invs<<<1, 64, 0, stream>>>(csump, inv_s);
  k5b_disp<<<512, 256, 0, stream>>>(num, inv_s, o_disp);
  k6_slotin<<<256, 256, 0, stream>>>(x, num, part6);
  k8_h<<<256, 256, 0, stream>>>(part6, W1, rawh);
  k10_so<<<256, 256, 0, stream>>>(rawh, W2, b1, inv_s, part10);
  k11_sofin<<<128, 256, 0, stream>>>(part10, b2, slot_out);
  k12_out<<<512, 256, 0, stream>>>(slot_out, combine, o_out);
}